// Round 16
// baseline (340.309 us; speedup 1.0000x reference)
//
#include <hip/hip_runtime.h>

// K-Sparse Autoencoder fwd: B=4096, D=768, H=16384, K=32
// Round-15 code with ONE change: finalize's z zero-fill is DRIPPED through the gather loop
// (2 nt stores per candidate iteration, no barrier in between -> stores retire under the
// ~75us gather phase; post-gather/post-topk barriers drain before scatter).
// Determinism notes (tripwire discipline):
//  - no cross-call state; candidate SET deterministic; top-32 total-ordered; padding si=-1
//  - GEMM pipeline: barriers/waits wave-uniform; stage target buf (kt+3)%4 provably dead;
//    NO other VMEM ops inside the counted-vmcnt loop (round-10 lesson)
//  - zero stores and scatter ordered by the two __syncthreads (each drains vmcnt(0))
constexpr int NB = 4096;
constexpr int ND = 768;
constexpr int NH = 16384;
constexpr int NK = 32;
constexpr int CAND_MAX = 512;
#define DELTA 0.025f  // >= 2*(MFMA dot err ~0.009 + bf16 store quant ~0.004); measured-safe

typedef __bf16 bf16x8 __attribute__((ext_vector_type(8)));
typedef float  f32x4  __attribute__((ext_vector_type(4)));
typedef unsigned int u32x4 __attribute__((ext_vector_type(4)));

// ---------------- workspace layout (bytes) ----------------
constexpr size_t OFF_XBF   = 0;                                     // x bf16      [NB][ND]
constexpr size_t OFF_WENCB = OFF_XBF   + (size_t)NB * ND * 2;       // W_enc bf16  [NH][ND]
constexpr size_t OFF_WDECT = OFF_WENCB + (size_t)NH * ND * 2;       // W_dec^T f32 [NH][ND]
constexpr size_t OFF_CIDX  = OFF_WDECT + (size_t)NH * ND * 4;       // cand_idx (fallback)
constexpr size_t OFF_CCNT  = OFF_CIDX  + (size_t)NB * CAND_MAX * 4; // cand_cnt (fallback)
constexpr size_t OFF_ZA    = OFF_CCNT  + (size_t)NB * 4;            // za bf16 [NB][NH] (fused)
constexpr size_t ZA_BYTES  = (size_t)NB * NH * 2;

__device__ inline unsigned short f2bf(float f) {
  unsigned u = __float_as_uint(f);
  unsigned r = u + 0x7fffu + ((u >> 16) & 1u);   // RNE
  return (unsigned short)(r >> 16);
}

__device__ __forceinline__ void gld_lds16(const unsigned short* g, unsigned short* s) {
  __builtin_amdgcn_global_load_lds((const __attribute__((address_space(1))) void*)g,
                                   (__attribute__((address_space(3))) void*)s, 16, 0, 0);
}

// ---------------- K1: merged prep (cast x, cast W_enc, transpose W_dec) ----------------
__global__ __launch_bounds__(256) void prep_kernel(
    const float* __restrict__ x, unsigned short* __restrict__ x_bf,
    const float* __restrict__ W_enc, unsigned short* __restrict__ wenc_bf,
    const float* __restrict__ W_dec, float* __restrict__ wdecT) {
  int b = blockIdx.x, tid = threadIdx.x;
  if (b < 1024) {                       // cast x
    int n4 = NB * ND / 4, stride = 1024 * 256;
    for (int i = b * 256 + tid; i < n4; i += stride) {
      float4 v = ((const float4*)x)[i];
      unsigned long long p = (unsigned long long)f2bf(v.x)
                           | ((unsigned long long)f2bf(v.y) << 16)
                           | ((unsigned long long)f2bf(v.z) << 32)
                           | ((unsigned long long)f2bf(v.w) << 48);
      ((unsigned long long*)x_bf)[i] = p;
    }
  } else if (b < 3072) {                // cast W_enc
    int n4 = NH * ND / 4, stride = 2048 * 256;
    for (int i = (b - 1024) * 256 + tid; i < n4; i += stride) {
      float4 v = ((const float4*)W_enc)[i];
      unsigned long long p = (unsigned long long)f2bf(v.x)
                           | ((unsigned long long)f2bf(v.y) << 16)
                           | ((unsigned long long)f2bf(v.z) << 32)
                           | ((unsigned long long)f2bf(v.w) << 48);
      ((unsigned long long*)wenc_bf)[i] = p;
    }
  } else {                              // transpose W_dec: 512 x 24 tiles of 32x32
    __shared__ float tile[32][33];
    int tb = b - 3072;
    int hb = (tb & 511) * 32, db = (tb >> 9) * 32;
    int tx = tid & 31, ty = tid >> 5;   // 32 x 8
#pragma unroll
    for (int i = 0; i < 4; ++i)
      tile[ty + i * 8][tx] = W_dec[(size_t)(db + ty + i * 8) * NH + hb + tx];
    __syncthreads();
#pragma unroll
    for (int i = 0; i < 4; ++i)
      wdecT[(size_t)(hb + ty + i * 8) * ND + db + tx] = tile[tx][ty + i * 8];
  }
}

// ---------------- K3: encode GEMM 256x256, BK=32, 8 waves, 4-buffer prefetch-3 pipeline ----
// (round-15 form, frozen)
__global__ __launch_bounds__(512) void encode_gemm_kernel(
    const unsigned short* __restrict__ Abf,   // [NB][ND]
    const unsigned short* __restrict__ Bbf,   // [NH][ND]
    const float* __restrict__ b_enc,
    unsigned short* __restrict__ za) {        // [NB][NH] bf16
  __shared__ __align__(16) unsigned short lds_all[4 * 16384];   // 128 KB

  int bid = blockIdx.x;                 // 0..1023
  int xx = bid & 7;
  int jj = bid >> 3;
  int st = jj >> 4;
  int w  = jj & 15;
  int g  = st * 8 + xx;
  int bm = (g & 3) * 4 + (w & 3);
  int bn = (g >> 2) * 4 + (w >> 2);
  int m0 = bm * 256, n0 = bn * 256;

  int tid = threadIdx.x;                // 0..511
  int wid = tid >> 6, l = tid & 63;
  int wr = wid >> 2, wc = wid & 3;      // 2 M-waves x 4 N-waves
  int lr = l & 15, lk = l >> 4;

#define STAGE_A(nbuf, ktile, t) do {                                              \
    int c_ = (t) * 512 + tid; int r_ = c_ >> 2;                                   \
    int lu_ = (c_ & 3) ^ ((r_ >> 1) & 3);                                         \
    gld_lds16(Abf + (size_t)(m0 + r_) * ND + (ktile) * 32 + lu_ * 8,              \
              lds_all + (nbuf) * 16384 + ((t) * 512 + (wid << 6)) * 8);           \
  } while (0)
#define STAGE_B(nbuf, ktile, t) do {                                              \
    int c_ = (t) * 512 + tid; int r_ = c_ >> 2;                                   \
    int lu_ = (c_ & 3) ^ ((r_ >> 1) & 3);                                         \
    gld_lds16(Bbf + (size_t)(n0 + r_) * ND + (ktile) * 32 + lu_ * 8,              \
              lds_all + (nbuf) * 16384 + 8192 + ((t) * 512 + (wid << 6)) * 8);    \
  } while (0)

  f32x4 acc[8][4] = {};

  STAGE_A(0, 0, 0); STAGE_A(0, 0, 1); STAGE_B(0, 0, 0); STAGE_B(0, 0, 1);
  STAGE_A(1, 1, 0); STAGE_A(1, 1, 1); STAGE_B(1, 1, 0); STAGE_B(1, 1, 1);
  STAGE_A(2, 2, 0); STAGE_A(2, 2, 1); STAGE_B(2, 2, 0); STAGE_B(2, 2, 1);
  asm volatile("s_waitcnt vmcnt(8)" ::: "memory");
  __builtin_amdgcn_s_barrier();
  __builtin_amdgcn_sched_barrier(0);

  int cur = 0;
  for (int kt = 0; kt < 24; ++kt) {     // ND/32
    int nx = (cur + 3) & 3;
    const unsigned short* Ab = lds_all + cur * 16384;
    const unsigned short* Bb = Ab + 8192;
    bf16x8 aF[4], bF[4];

#pragma unroll
    for (int fj = 0; fj < 4; ++fj) {
      int row = wc * 64 + fj * 16 + lr;
      int pu = lk ^ ((row >> 1) & 3);
      bF[fj] = *(const bf16x8*)(Bb + row * 32 + pu * 8);
    }
#pragma unroll
    for (int fi = 0; fi < 4; ++fi) {
      int row = wr * 128 + fi * 16 + lr;
      int pu = lk ^ ((row >> 1) & 3);
      aF[fi] = *(const bf16x8*)(Ab + row * 32 + pu * 8);
    }
    if (kt < 21) { STAGE_A(nx, kt + 3, 0); STAGE_A(nx, kt + 3, 1); }
    __builtin_amdgcn_s_setprio(1);
#pragma unroll
    for (int fi = 0; fi < 4; ++fi)
#pragma unroll
      for (int fj = 0; fj < 4; ++fj)
        acc[fi][fj] = __builtin_amdgcn_mfma_f32_16x16x32_bf16(aF[fi], bF[fj], acc[fi][fj], 0, 0, 0);
    __builtin_amdgcn_s_setprio(0);

#pragma unroll
    for (int fi = 0; fi < 4; ++fi) {
      int row = wr * 128 + (4 + fi) * 16 + lr;
      int pu = lk ^ ((row >> 1) & 3);
      aF[fi] = *(const bf16x8*)(Ab + row * 32 + pu * 8);
    }
    if (kt < 21) { STAGE_B(nx, kt + 3, 0); STAGE_B(nx, kt + 3, 1); }
    __builtin_amdgcn_s_setprio(1);
#pragma unroll
    for (int fi = 0; fi < 4; ++fi)
#pragma unroll
      for (int fj = 0; fj < 4; ++fj)
        acc[4 + fi][fj] = __builtin_amdgcn_mfma_f32_16x16x32_bf16(aF[fi], bF[fj], acc[4 + fi][fj], 0, 0, 0);
    __builtin_amdgcn_s_setprio(0);

    if (kt < 23) {
      if (kt <= 20)      asm volatile("s_waitcnt vmcnt(8)" ::: "memory");
      else if (kt == 21) asm volatile("s_waitcnt vmcnt(4)" ::: "memory");
      else               asm volatile("s_waitcnt vmcnt(0)" ::: "memory");
      __builtin_amdgcn_s_barrier();
      __builtin_amdgcn_sched_barrier(0);
    }
    cur = (cur + 1) & 3;
  }
#undef STAGE_A
#undef STAGE_B

  __syncthreads();
  unsigned short* ep = lds_all + wid * 4096;
#pragma unroll
  for (int half = 0; half < 2; ++half) {
#pragma unroll
    for (int fj = 0; fj < 4; ++fj) {
      float bias = b_enc[n0 + wc * 64 + fj * 16 + lr];
#pragma unroll
      for (int i2 = 0; i2 < 4; ++i2) {
#pragma unroll
        for (int q = 0; q < 4; ++q) {
          int row = i2 * 16 + lk * 4 + q;
          int col = fj * 16 + lr;
          float v = fmaxf(acc[half * 4 + i2][fj][q] + bias, 0.0f);
          ep[row * 64 + (((col >> 3) ^ (row & 7)) * 8) + (col & 7)] = f2bf(v);
        }
      }
    }
    __syncthreads();
#pragma unroll
    for (int t = 0; t < 8; ++t) {
      int row = t * 8 + (l >> 3);
      int u = (l & 7) ^ (row & 7);
      int4 d = *(const int4*)&ep[row * 64 + u * 8];
      *(int4*)(za + (size_t)(m0 + wr * 128 + half * 64 + row) * NH
                    + n0 + wc * 64 + (l & 7) * 8) = d;
    }
    __syncthreads();
  }
}

// ======== shared device helpers ========

__device__ __forceinline__ float bisect_thr(const u32x4* v, int* wcnt, int tid) {
  unsigned lo = 0u, hi = 0x7F80u;
  for (int it = 0; it < 15; ++it) {
    unsigned mid = (lo + hi) >> 1;
    int c = 0;
#pragma unroll
    for (int i = 0; i < 8; ++i) {
      const unsigned* p = (const unsigned*)&v[i];
#pragma unroll
      for (int e = 0; e < 4; ++e) {
        unsigned u = p[e];
        c += ((u & 0xFFFFu) >= mid) ? 1 : 0;
        c += ((u >> 16) >= mid) ? 1 : 0;
      }
    }
#pragma unroll
    for (int off = 32; off; off >>= 1) c += __shfl_xor(c, off, 64);
    if ((tid & 63) == 0) wcnt[tid >> 6] = c;
    __syncthreads();
    int tot = wcnt[0] + wcnt[1] + wcnt[2] + wcnt[3];
    __syncthreads();
    if (tot >= NK) {
      lo = mid;
      if (tot <= 48) break;
    } else {
      hi = mid;
    }
  }
  float thr = __uint_as_float(lo << 16) - DELTA;
  return (thr < 1e-12f) ? 1e-12f : thr;
}

__device__ __forceinline__ void topk_wave0(const float* cv, const int* ci, int cnt,
                                           float* sv, int* si, int l) {
  float lv[8]; int lh[8];
#pragma unroll
  for (int ii = 0; ii < 8; ++ii) {
    int c = l + 64 * ii;
    if (c < cnt) { lv[ii] = cv[c]; lh[ii] = ci[c]; }
    else         { lv[ii] = -1.f;  lh[ii] = 0x7fffffff; }
  }
  for (int r = 0; r < NK; ++r) {
    float bv = -1.f; int bh = 0x7fffffff; int bl = l; int bii = 0;
#pragma unroll
    for (int ii = 0; ii < 8; ++ii)
      if (lv[ii] > bv || (lv[ii] == bv && lh[ii] < bh)) { bv = lv[ii]; bh = lh[ii]; bii = ii; }
#pragma unroll
    for (int off = 32; off; off >>= 1) {
      float ov = __shfl_xor(bv, off, 64);
      int   oh = __shfl_xor(bh, off, 64);
      int   ol = __shfl_xor(bl, off, 64);
      int   oi = __shfl_xor(bii, off, 64);
      if (ov > bv || (ov == bv && oh < bh)) { bv = ov; bh = oh; bl = ol; bii = oi; }
    }
    if (l == 0) {
      if (bv > -0.5f) { sv[r] = bv; si[r] = bh; }
      else            { sv[r] = 0.f; si[r] = -1; }
    }
#pragma unroll
    for (int ii = 0; ii < 8; ++ii)
      if (ii == bii && l == bl && bv > -0.5f) lv[ii] = -1.f;
  }
}

// ---------------- K4 (fallback): select ----------------
__global__ __launch_bounds__(256) void select_kernel(const unsigned short* __restrict__ za,
                                                     int* __restrict__ cand_idx,
                                                     int* __restrict__ cand_cnt) {
  int b = blockIdx.x, tid = threadIdx.x;
  const u32x4* zrow = (const u32x4*)(za + (size_t)b * NH);
  u32x4 v[8];
#pragma unroll
  for (int i = 0; i < 8; ++i) v[i] = __builtin_nontemporal_load(zrow + tid + 256 * i);

  __shared__ int wcnt[4];
  __shared__ int lcnt;
  float thr = bisect_thr(v, wcnt, tid);
  if (tid == 0) lcnt = 0;
  __syncthreads();
#pragma unroll
  for (int i = 0; i < 8; ++i) {
    const unsigned* p = (const unsigned*)&v[i];
#pragma unroll
    for (int e = 0; e < 4; ++e) {
      unsigned u = p[e];
      int hbase = (tid + 256 * i) * 8 + e * 2;
      float f0 = __uint_as_float((u & 0xFFFFu) << 16);
      float f1 = __uint_as_float(u & 0xFFFF0000u);
      if (f0 >= thr) { int s = atomicAdd(&lcnt, 1); if (s < CAND_MAX) cand_idx[(size_t)b * CAND_MAX + s] = hbase; }
      if (f1 >= thr) { int s = atomicAdd(&lcnt, 1); if (s < CAND_MAX) cand_idx[(size_t)b * CAND_MAX + s] = hbase + 1; }
    }
  }
  __syncthreads();
  if (tid == 0) cand_cnt[b] = (lcnt < CAND_MAX) ? lcnt : CAND_MAX;
}

// ======== finalize core: {ILP-2 gather || dripped nt-zero} -> topk -> scatter + decode ========
__device__ __forceinline__ void finalize_core(
    int b, int tid, int wid, int l, int cnt,
    const float* __restrict__ W_enc, const float* __restrict__ b_enc,
    const float* __restrict__ WdecT, const float* __restrict__ b_dec,
    const float* xr, float* cv, const int* ci, float* sv, int* si,
    float* __restrict__ zout, float* __restrict__ xhat) {
  const float4* xr4 = (const float4*)xr;
  float4 xv[3];
#pragma unroll
  for (int i = 0; i < 3; ++i) xv[i] = xr4[l + 64 * i];

  // z zero-fill state: 16 nt stores/thread (256 threads x 16 x 16B = 64 KB row), dripped
  // through the gather loop. No barrier inside the loop -> stores retire under gather latency.
  f32x4 zz = {0.f, 0.f, 0.f, 0.f};
  f32x4* zr = (f32x4*)(zout + (size_t)b * NH);
  int zi = 0;

  for (int c0 = wid; c0 < cnt; c0 += 8) {     // 2 candidates per iteration (ILP)
    int c1 = c0 + 4;
    bool has1 = (c1 < cnt);
    int h0 = ci[c0];
    int h1 = has1 ? ci[c1] : h0;
    const float4* w0 = (const float4*)(W_enc + (size_t)h0 * ND);
    const float4* w1 = (const float4*)(W_enc + (size_t)h1 * ND);
    float4 wv0[3], wv1[3];
#pragma unroll
    for (int i = 0; i < 3; ++i) { wv0[i] = w0[l + 64 * i]; wv1[i] = w1[l + 64 * i]; }
    if (zi < 16) {                            // drip 2 zero stores behind the gather loads
      __builtin_nontemporal_store(zz, zr + tid + 256 * zi); ++zi;
      __builtin_nontemporal_store(zz, zr + tid + 256 * zi); ++zi;
    }
    float4 a0 = {0.f, 0.f, 0.f, 0.f}, a1 = {0.f, 0.f, 0.f, 0.f};
#pragma unroll
    for (int i = 0; i < 3; ++i) {
      a0.x = fmaf(wv0[i].x, xv[i].x, a0.x); a1.x = fmaf(wv1[i].x, xv[i].x, a1.x);
      a0.y = fmaf(wv0[i].y, xv[i].y, a0.y); a1.y = fmaf(wv1[i].y, xv[i].y, a1.y);
      a0.z = fmaf(wv0[i].z, xv[i].z, a0.z); a1.z = fmaf(wv1[i].z, xv[i].z, a1.z);
      a0.w = fmaf(wv0[i].w, xv[i].w, a0.w); a1.w = fmaf(wv1[i].w, xv[i].w, a1.w);
    }
    float s0 = (a0.x + a0.y) + (a0.z + a0.w);
    float s1 = (a1.x + a1.y) + (a1.z + a1.w);
#pragma unroll
    for (int off = 32; off; off >>= 1) {
      s0 += __shfl_xor(s0, off, 64);
      s1 += __shfl_xor(s1, off, 64);
    }
    if (l == 0) {
      cv[c0] = fmaxf(s0 + b_enc[h0], 0.f);
      if (has1) cv[c1] = fmaxf(s1 + b_enc[h1], 0.f);
    }
  }
  // flush remaining zero stores (short-cnt rows)
  for (; zi < 16; ++zi) __builtin_nontemporal_store(zz, zr + tid + 256 * zi);
  __syncthreads();                             // drains vmcnt(0): gathers AND zero stores done

  if (wid == 0) topk_wave0(cv, ci, cnt, sv, si, l);
  __syncthreads();                             // sv/si visible; all waves' stores long drained

  if (tid < NK) {
    int s = si[tid];
    if (s >= 0) zout[(size_t)b * NH + s] = sv[tid];
  }

  if (tid < ND / 4) {
    float4 a = ((const float4*)b_dec)[tid];
#pragma unroll 8
    for (int j = 0; j < NK; ++j) {
      int hj = si[j]; hj = (hj < 0) ? 0 : hj;
      float vj = sv[j];
      float4 wv = ((const float4*)(WdecT + (size_t)hj * ND))[tid];
      a.x = fmaf(vj, wv.x, a.x);
      a.y = fmaf(vj, wv.y, a.y);
      a.z = fmaf(vj, wv.z, a.z);
      a.w = fmaf(vj, wv.w, a.w);
    }
    ((float4*)(xhat + (size_t)b * ND))[tid] = a;
  }
}

// ---------------- K5 (fallback): finalize from cidx/ccnt ----------------
__global__ __launch_bounds__(256) void finalize_kernel(
    const float* __restrict__ x, const float* __restrict__ W_enc,
    const float* __restrict__ b_enc,
    const int* __restrict__ cand_idx, const int* __restrict__ cand_cnt,
    const float* __restrict__ WdecT, const float* __restrict__ b_dec,
    float* __restrict__ zout, float* __restrict__ xhat) {
  int b = blockIdx.x, tid = threadIdx.x;
  int wid = tid >> 6, l = tid & 63;
  __shared__ __align__(16) float xr[ND];
  __shared__ float cv[CAND_MAX];
  __shared__ int   ci[CAND_MAX];
  __shared__ float sv[NK];
  __shared__ int   si[NK];

  int cnt = cand_cnt[b];
  const float4* xrow = (const float4*)(x + (size_t)b * ND);
  for (int i = tid; i < ND / 4; i += 256) ((float4*)xr)[i] = xrow[i];
  for (int c = tid; c < cnt; c += 256) ci[c] = cand_idx[(size_t)b * CAND_MAX + c];
  __syncthreads();
  finalize_core(b, tid, wid, l, cnt, W_enc, b_enc, WdecT, b_dec,
                xr, cv, ci, sv, si, zout, xhat);
}

// ---------------- K4+K5 (fused): select+finalize ----------------
__global__ __launch_bounds__(256) void fused_finalize_kernel(
    const unsigned short* __restrict__ za,
    const float* __restrict__ x, const float* __restrict__ W_enc,
    const float* __restrict__ b_enc,
    const float* __restrict__ WdecT, const float* __restrict__ b_dec,
    float* __restrict__ zout, float* __restrict__ xhat) {
  int b = blockIdx.x, tid = threadIdx.x;
  int wid = tid >> 6, l = tid & 63;
  __shared__ __align__(16) float xr[ND];
  __shared__ float cv[CAND_MAX];
  __shared__ int   ci[CAND_MAX];
  __shared__ float sv[NK];
  __shared__ int   si[NK];
  __shared__ int   wcnt[4];
  __shared__ int   lcnt;

  const u32x4* zrow = (const u32x4*)(za + (size_t)b * NH);
  u32x4 v[8];
#pragma unroll
  for (int i = 0; i < 8; ++i) v[i] = __builtin_nontemporal_load(zrow + tid + 256 * i);
  const f32x4* xrow = (const f32x4*)(x + (size_t)b * ND);
  for (int i = tid; i < ND / 4; i += 256)
    ((f32x4*)xr)[i] = __builtin_nontemporal_load(xrow + i);

  float thr = bisect_thr(v, wcnt, tid);
  if (tid == 0) lcnt = 0;
  __syncthreads();
#pragma unroll
  for (int i = 0; i < 8; ++i) {
    const unsigned* p = (const unsigned*)&v[i];
#pragma unroll
    for (int e = 0; e < 4; ++e) {
      unsigned u = p[e];
      int hbase = (tid + 256 * i) * 8 + e * 2;
      float f0 = __uint_as_float((u & 0xFFFFu) << 16);
      float f1 = __uint_as_float(u & 0xFFFF0000u);
      if (f0 >= thr) { int s = atomicAdd(&lcnt, 1); if (s < CAND_MAX) ci[s] = hbase; }
      if (f1 >= thr) { int s = atomicAdd(&lcnt, 1); if (s < CAND_MAX) ci[s] = hbase + 1; }
    }
  }
  __syncthreads();
  int cnt = (lcnt < CAND_MAX) ? lcnt : CAND_MAX;

  finalize_core(b, tid, wid, l, cnt, W_enc, b_enc, WdecT, b_dec,
                xr, cv, ci, sv, si, zout, xhat);
}

// ---------------- launcher ----------------
extern "C" void kernel_launch(void* const* d_in, const int* in_sizes, int n_in,
                              void* d_out, int out_size, void* d_ws, size_t ws_size,
                              hipStream_t stream) {
  const float* x     = (const float*)d_in[0];
  const float* W_enc = (const float*)d_in[1];
  const float* b_enc = (const float*)d_in[2];
  const float* W_dec = (const float*)d_in[3];
  const float* b_dec = (const float*)d_in[4];

  float* xhat = (float*)d_out;
  float* zout = (float*)d_out + (size_t)NB * ND;

  char* ws = (char*)d_ws;
  unsigned short* x_bf    = (unsigned short*)(ws + OFF_XBF);
  unsigned short* wenc_bf = (unsigned short*)(ws + OFF_WENCB);
  float*          wdecT   = (float*)(ws + OFF_WDECT);
  int*            cidx    = (int*)(ws + OFF_CIDX);
  int*            ccnt    = (int*)(ws + OFF_CCNT);

  bool fused = ws_size >= OFF_ZA + ZA_BYTES;   // constant across calls -> capture-safe
  unsigned short* za = fused ? (unsigned short*)(ws + OFF_ZA)
                             : (unsigned short*)zout;

  prep_kernel<<<15360, 256, 0, stream>>>(x, x_bf, W_enc, wenc_bf, W_dec, wdecT);
  encode_gemm_kernel<<<(NB / 256) * (NH / 256), 512, 0, stream>>>(x_bf, wenc_bf, b_enc, za);
  if (fused) {
    fused_finalize_kernel<<<NB, 256, 0, stream>>>(za, x, W_enc, b_enc, wdecT, b_dec, zout, xhat);
  } else {
    select_kernel<<<NB, 256, 0, stream>>>(za, cidx, ccnt);
    finalize_kernel<<<NB, 256, 0, stream>>>(x, W_enc, b_enc, cidx, ccnt, wdecT, b_dec, zout, xhat);
  }
}

// Round 17
// 338.155 us; speedup vs baseline: 1.0064x; 1.0064x over previous
//
#include <hip/hip_runtime.h>

// K-Sparse Autoencoder fwd: B=4096, D=768, H=16384, K=32
// Round-15 base (best, 333us) with ONE change: GEMM K-loop gets m201-style per-phase
// barrier pairs around each MFMA cluster (8-phase schedule, T3+T5). Memory discipline
// (4-buf, prefetch-3, counted vmcnt(8) at tile boundary) unchanged.
// Determinism notes (tripwire discipline):
//  - no cross-call state; candidate SET deterministic; top-32 total-ordered; padding si=-1
//  - GEMM: all barriers wave-uniform; stage target buf (kt+3)%4 provably dead; extra
//    per-phase barriers only ADD sync; NO other VMEM ops inside the counted-vmcnt loop
//  - z zero-fill: topk slot (waves 1-3), nt stores; post-topk barrier drains before scatter
constexpr int NB = 4096;
constexpr int ND = 768;
constexpr int NH = 16384;
constexpr int NK = 32;
constexpr int CAND_MAX = 512;
#define DELTA 0.025f  // >= 2*(MFMA dot err ~0.009 + bf16 store quant ~0.004); measured-safe

typedef __bf16 bf16x8 __attribute__((ext_vector_type(8)));
typedef float  f32x4  __attribute__((ext_vector_type(4)));
typedef unsigned int u32x4 __attribute__((ext_vector_type(4)));

// ---------------- workspace layout (bytes) ----------------
constexpr size_t OFF_XBF   = 0;                                     // x bf16      [NB][ND]
constexpr size_t OFF_WENCB = OFF_XBF   + (size_t)NB * ND * 2;       // W_enc bf16  [NH][ND]
constexpr size_t OFF_WDECT = OFF_WENCB + (size_t)NH * ND * 2;       // W_dec^T f32 [NH][ND]
constexpr size_t OFF_CIDX  = OFF_WDECT + (size_t)NH * ND * 4;       // cand_idx (fallback)
constexpr size_t OFF_CCNT  = OFF_CIDX  + (size_t)NB * CAND_MAX * 4; // cand_cnt (fallback)
constexpr size_t OFF_ZA    = OFF_CCNT  + (size_t)NB * 4;            // za bf16 [NB][NH] (fused)
constexpr size_t ZA_BYTES  = (size_t)NB * NH * 2;

__device__ inline unsigned short f2bf(float f) {
  unsigned u = __float_as_uint(f);
  unsigned r = u + 0x7fffu + ((u >> 16) & 1u);   // RNE
  return (unsigned short)(r >> 16);
}

__device__ __forceinline__ void gld_lds16(const unsigned short* g, unsigned short* s) {
  __builtin_amdgcn_global_load_lds((const __attribute__((address_space(1))) void*)g,
                                   (__attribute__((address_space(3))) void*)s, 16, 0, 0);
}

// ---------------- K1: merged prep (cast x, cast W_enc, transpose W_dec) ----------------
__global__ __launch_bounds__(256) void prep_kernel(
    const float* __restrict__ x, unsigned short* __restrict__ x_bf,
    const float* __restrict__ W_enc, unsigned short* __restrict__ wenc_bf,
    const float* __restrict__ W_dec, float* __restrict__ wdecT) {
  int b = blockIdx.x, tid = threadIdx.x;
  if (b < 1024) {                       // cast x
    int n4 = NB * ND / 4, stride = 1024 * 256;
    for (int i = b * 256 + tid; i < n4; i += stride) {
      float4 v = ((const float4*)x)[i];
      unsigned long long p = (unsigned long long)f2bf(v.x)
                           | ((unsigned long long)f2bf(v.y) << 16)
                           | ((unsigned long long)f2bf(v.z) << 32)
                           | ((unsigned long long)f2bf(v.w) << 48);
      ((unsigned long long*)x_bf)[i] = p;
    }
  } else if (b < 3072) {                // cast W_enc
    int n4 = NH * ND / 4, stride = 2048 * 256;
    for (int i = (b - 1024) * 256 + tid; i < n4; i += stride) {
      float4 v = ((const float4*)W_enc)[i];
      unsigned long long p = (unsigned long long)f2bf(v.x)
                           | ((unsigned long long)f2bf(v.y) << 16)
                           | ((unsigned long long)f2bf(v.z) << 32)
                           | ((unsigned long long)f2bf(v.w) << 48);
      ((unsigned long long*)wenc_bf)[i] = p;
    }
  } else {                              // transpose W_dec: 512 x 24 tiles of 32x32
    __shared__ float tile[32][33];
    int tb = b - 3072;
    int hb = (tb & 511) * 32, db = (tb >> 9) * 32;
    int tx = tid & 31, ty = tid >> 5;   // 32 x 8
#pragma unroll
    for (int i = 0; i < 4; ++i)
      tile[ty + i * 8][tx] = W_dec[(size_t)(db + ty + i * 8) * NH + hb + tx];
    __syncthreads();
#pragma unroll
    for (int i = 0; i < 4; ++i)
      wdecT[(size_t)(hb + ty + i * 8) * ND + db + tx] = tile[tx][ty + i * 8];
  }
}

// ---------------- K3: encode GEMM 256x256, BK=32, 8 waves, 4-buf prefetch-3, 8-phase ----
__global__ __launch_bounds__(512) void encode_gemm_kernel(
    const unsigned short* __restrict__ Abf,   // [NB][ND]
    const unsigned short* __restrict__ Bbf,   // [NH][ND]
    const float* __restrict__ b_enc,
    unsigned short* __restrict__ za) {        // [NB][NH] bf16
  __shared__ __align__(16) unsigned short lds_all[4 * 16384];   // 128 KB

  int bid = blockIdx.x;                 // 0..1023
  int xx = bid & 7;
  int jj = bid >> 3;
  int st = jj >> 4;
  int w  = jj & 15;
  int g  = st * 8 + xx;
  int bm = (g & 3) * 4 + (w & 3);
  int bn = (g >> 2) * 4 + (w >> 2);
  int m0 = bm * 256, n0 = bn * 256;

  int tid = threadIdx.x;                // 0..511
  int wid = tid >> 6, l = tid & 63;
  int wr = wid >> 2, wc = wid & 3;      // 2 M-waves x 4 N-waves
  int lr = l & 15, lk = l >> 4;

#define STAGE_A(nbuf, ktile, t) do {                                              \
    int c_ = (t) * 512 + tid; int r_ = c_ >> 2;                                   \
    int lu_ = (c_ & 3) ^ ((r_ >> 1) & 3);                                         \
    gld_lds16(Abf + (size_t)(m0 + r_) * ND + (ktile) * 32 + lu_ * 8,              \
              lds_all + (nbuf) * 16384 + ((t) * 512 + (wid << 6)) * 8);           \
  } while (0)
#define STAGE_B(nbuf, ktile, t) do {                                              \
    int c_ = (t) * 512 + tid; int r_ = c_ >> 2;                                   \
    int lu_ = (c_ & 3) ^ ((r_ >> 1) & 3);                                         \
    gld_lds16(Bbf + (size_t)(n0 + r_) * ND + (ktile) * 32 + lu_ * 8,              \
              lds_all + (nbuf) * 16384 + 8192 + ((t) * 512 + (wid << 6)) * 8);    \
  } while (0)

  f32x4 acc[8][4] = {};

  STAGE_A(0, 0, 0); STAGE_A(0, 0, 1); STAGE_B(0, 0, 0); STAGE_B(0, 0, 1);
  STAGE_A(1, 1, 0); STAGE_A(1, 1, 1); STAGE_B(1, 1, 0); STAGE_B(1, 1, 1);
  STAGE_A(2, 2, 0); STAGE_A(2, 2, 1); STAGE_B(2, 2, 0); STAGE_B(2, 2, 1);
  asm volatile("s_waitcnt vmcnt(8)" ::: "memory");
  __builtin_amdgcn_s_barrier();
  __builtin_amdgcn_sched_barrier(0);

  int cur = 0;
  for (int kt = 0; kt < 24; ++kt) {     // ND/32
    int nx = (cur + 3) & 3;
    const unsigned short* Ab = lds_all + cur * 16384;
    const unsigned short* Bb = Ab + 8192;
    bf16x8 aF[4], bF[4];

    // ---- phase 1: {ds_read bF(4)+aF0-3(4) || STAGE_A(kt+3)} -> bar -> MFMA16 -> bar ----
#pragma unroll
    for (int fj = 0; fj < 4; ++fj) {
      int row = wc * 64 + fj * 16 + lr;
      int pu = lk ^ ((row >> 1) & 3);
      bF[fj] = *(const bf16x8*)(Bb + row * 32 + pu * 8);
    }
#pragma unroll
    for (int fi = 0; fi < 4; ++fi) {
      int row = wr * 128 + fi * 16 + lr;
      int pu = lk ^ ((row >> 1) & 3);
      aF[fi] = *(const bf16x8*)(Ab + row * 32 + pu * 8);
    }
    if (kt < 21) { STAGE_A(nx, kt + 3, 0); STAGE_A(nx, kt + 3, 1); }
    __builtin_amdgcn_s_barrier();            // phase-align (raw: no counter drain)
    __builtin_amdgcn_sched_barrier(0);
    __builtin_amdgcn_s_setprio(1);
#pragma unroll
    for (int fi = 0; fi < 4; ++fi)
#pragma unroll
      for (int fj = 0; fj < 4; ++fj)
        acc[fi][fj] = __builtin_amdgcn_mfma_f32_16x16x32_bf16(aF[fi], bF[fj], acc[fi][fj], 0, 0, 0);
    __builtin_amdgcn_s_setprio(0);
    __builtin_amdgcn_s_barrier();
    __builtin_amdgcn_sched_barrier(0);

    // ---- phase 2: {ds_read aF4-7(4) || STAGE_B(kt+3)} -> bar -> MFMA16 -> boundary ----
#pragma unroll
    for (int fi = 0; fi < 4; ++fi) {
      int row = wr * 128 + (4 + fi) * 16 + lr;
      int pu = lk ^ ((row >> 1) & 3);
      aF[fi] = *(const bf16x8*)(Ab + row * 32 + pu * 8);
    }
    if (kt < 21) { STAGE_B(nx, kt + 3, 0); STAGE_B(nx, kt + 3, 1); }
    __builtin_amdgcn_s_barrier();
    __builtin_amdgcn_sched_barrier(0);
    __builtin_amdgcn_s_setprio(1);
#pragma unroll
    for (int fi = 0; fi < 4; ++fi)
#pragma unroll
      for (int fj = 0; fj < 4; ++fj)
        acc[4 + fi][fj] = __builtin_amdgcn_mfma_f32_16x16x32_bf16(aF[fi], bF[fj], acc[4 + fi][fj], 0, 0, 0);
    __builtin_amdgcn_s_setprio(0);

    // ---- tile boundary: counted wait (kt+1 resident; kt+2/kt+3 stay in flight) ----
    if (kt < 23) {
      if (kt <= 20)      asm volatile("s_waitcnt vmcnt(8)" ::: "memory");
      else if (kt == 21) asm volatile("s_waitcnt vmcnt(4)" ::: "memory");
      else               asm volatile("s_waitcnt vmcnt(0)" ::: "memory");
      __builtin_amdgcn_s_barrier();
      __builtin_amdgcn_sched_barrier(0);
    }
    cur = (cur + 1) & 3;
  }
#undef STAGE_A
#undef STAGE_B

  // ---- epilogue: bias+relu -> bf16 via LDS (two 64-row passes), coalesced 16B stores ----
  __syncthreads();
  unsigned short* ep = lds_all + wid * 4096;
#pragma unroll
  for (int half = 0; half < 2; ++half) {
#pragma unroll
    for (int fj = 0; fj < 4; ++fj) {
      float bias = b_enc[n0 + wc * 64 + fj * 16 + lr];
#pragma unroll
      for (int i2 = 0; i2 < 4; ++i2) {
#pragma unroll
        for (int q = 0; q < 4; ++q) {
          int row = i2 * 16 + lk * 4 + q;
          int col = fj * 16 + lr;
          float v = fmaxf(acc[half * 4 + i2][fj][q] + bias, 0.0f);
          ep[row * 64 + (((col >> 3) ^ (row & 7)) * 8) + (col & 7)] = f2bf(v);
        }
      }
    }
    __syncthreads();
#pragma unroll
    for (int t = 0; t < 8; ++t) {
      int row = t * 8 + (l >> 3);
      int u = (l & 7) ^ (row & 7);
      int4 d = *(const int4*)&ep[row * 64 + u * 8];
      *(int4*)(za + (size_t)(m0 + wr * 128 + half * 64 + row) * NH
                    + n0 + wc * 64 + (l & 7) * 8) = d;
    }
    __syncthreads();
  }
}

// ======== shared device helpers ========

__device__ __forceinline__ float bisect_thr(const u32x4* v, int* wcnt, int tid) {
  unsigned lo = 0u, hi = 0x7F80u;
  for (int it = 0; it < 15; ++it) {
    unsigned mid = (lo + hi) >> 1;
    int c = 0;
#pragma unroll
    for (int i = 0; i < 8; ++i) {
      const unsigned* p = (const unsigned*)&v[i];
#pragma unroll
      for (int e = 0; e < 4; ++e) {
        unsigned u = p[e];
        c += ((u & 0xFFFFu) >= mid) ? 1 : 0;
        c += ((u >> 16) >= mid) ? 1 : 0;
      }
    }
#pragma unroll
    for (int off = 32; off; off >>= 1) c += __shfl_xor(c, off, 64);
    if ((tid & 63) == 0) wcnt[tid >> 6] = c;
    __syncthreads();
    int tot = wcnt[0] + wcnt[1] + wcnt[2] + wcnt[3];
    __syncthreads();
    if (tot >= NK) {
      lo = mid;
      if (tot <= 48) break;
    } else {
      hi = mid;
    }
  }
  float thr = __uint_as_float(lo << 16) - DELTA;
  return (thr < 1e-12f) ? 1e-12f : thr;
}

__device__ __forceinline__ void topk_wave0(const float* cv, const int* ci, int cnt,
                                           float* sv, int* si, int l) {
  float lv[8]; int lh[8];
#pragma unroll
  for (int ii = 0; ii < 8; ++ii) {
    int c = l + 64 * ii;
    if (c < cnt) { lv[ii] = cv[c]; lh[ii] = ci[c]; }
    else         { lv[ii] = -1.f;  lh[ii] = 0x7fffffff; }
  }
  for (int r = 0; r < NK; ++r) {
    float bv = -1.f; int bh = 0x7fffffff; int bl = l; int bii = 0;
#pragma unroll
    for (int ii = 0; ii < 8; ++ii)
      if (lv[ii] > bv || (lv[ii] == bv && lh[ii] < bh)) { bv = lv[ii]; bh = lh[ii]; bii = ii; }
#pragma unroll
    for (int off = 32; off; off >>= 1) {
      float ov = __shfl_xor(bv, off, 64);
      int   oh = __shfl_xor(bh, off, 64);
      int   ol = __shfl_xor(bl, off, 64);
      int   oi = __shfl_xor(bii, off, 64);
      if (ov > bv || (ov == bv && oh < bh)) { bv = ov; bh = oh; bl = ol; bii = oi; }
    }
    if (l == 0) {
      if (bv > -0.5f) { sv[r] = bv; si[r] = bh; }
      else            { sv[r] = 0.f; si[r] = -1; }
    }
#pragma unroll
    for (int ii = 0; ii < 8; ++ii)
      if (ii == bii && l == bl && bv > -0.5f) lv[ii] = -1.f;
  }
}

// ---------------- K4 (fallback): select ----------------
__global__ __launch_bounds__(256) void select_kernel(const unsigned short* __restrict__ za,
                                                     int* __restrict__ cand_idx,
                                                     int* __restrict__ cand_cnt) {
  int b = blockIdx.x, tid = threadIdx.x;
  const u32x4* zrow = (const u32x4*)(za + (size_t)b * NH);
  u32x4 v[8];
#pragma unroll
  for (int i = 0; i < 8; ++i) v[i] = __builtin_nontemporal_load(zrow + tid + 256 * i);

  __shared__ int wcnt[4];
  __shared__ int lcnt;
  float thr = bisect_thr(v, wcnt, tid);
  if (tid == 0) lcnt = 0;
  __syncthreads();
#pragma unroll
  for (int i = 0; i < 8; ++i) {
    const unsigned* p = (const unsigned*)&v[i];
#pragma unroll
    for (int e = 0; e < 4; ++e) {
      unsigned u = p[e];
      int hbase = (tid + 256 * i) * 8 + e * 2;
      float f0 = __uint_as_float((u & 0xFFFFu) << 16);
      float f1 = __uint_as_float(u & 0xFFFF0000u);
      if (f0 >= thr) { int s = atomicAdd(&lcnt, 1); if (s < CAND_MAX) cand_idx[(size_t)b * CAND_MAX + s] = hbase; }
      if (f1 >= thr) { int s = atomicAdd(&lcnt, 1); if (s < CAND_MAX) cand_idx[(size_t)b * CAND_MAX + s] = hbase + 1; }
    }
  }
  __syncthreads();
  if (tid == 0) cand_cnt[b] = (lcnt < CAND_MAX) ? lcnt : CAND_MAX;
}

// ======== finalize core (round-12/15 proven): gather -> {topk || nt-zero} -> scatter+decode ==
__device__ __forceinline__ void finalize_core(
    int b, int tid, int wid, int l, int cnt,
    const float* __restrict__ W_enc, const float* __restrict__ b_enc,
    const float* __restrict__ WdecT, const float* __restrict__ b_dec,
    const float* xr, float* cv, const int* ci, float* sv, int* si,
    float* __restrict__ zout, float* __restrict__ xhat) {
  const float4* xr4 = (const float4*)xr;
  float4 xv[3];
#pragma unroll
  for (int i = 0; i < 3; ++i) xv[i] = xr4[l + 64 * i];

  for (int c0 = wid; c0 < cnt; c0 += 8) {     // 2 candidates per iteration (ILP)
    int c1 = c0 + 4;
    bool has1 = (c1 < cnt);
    int h0 = ci[c0];
    int h1 = has1 ? ci[c1] : h0;
    const float4* w0 = (const float4*)(W_enc + (size_t)h0 * ND);
    const float4* w1 = (const float4*)(W_enc + (size_t)h1 * ND);
    float4 wv0[3], wv1[3];
#pragma unroll
    for (int i = 0; i < 3; ++i) { wv0[i] = w0[l + 64 * i]; wv1[i] = w1[l + 64 * i]; }
    float4 a0 = {0.f, 0.f, 0.f, 0.f}, a1 = {0.f, 0.f, 0.f, 0.f};
#pragma unroll
    for (int i = 0; i < 3; ++i) {
      a0.x = fmaf(wv0[i].x, xv[i].x, a0.x); a1.x = fmaf(wv1[i].x, xv[i].x, a1.x);
      a0.y = fmaf(wv0[i].y, xv[i].y, a0.y); a1.y = fmaf(wv1[i].y, xv[i].y, a1.y);
      a0.z = fmaf(wv0[i].z, xv[i].z, a0.z); a1.z = fmaf(wv1[i].z, xv[i].z, a1.z);
      a0.w = fmaf(wv0[i].w, xv[i].w, a0.w); a1.w = fmaf(wv1[i].w, xv[i].w, a1.w);
    }
    float s0 = (a0.x + a0.y) + (a0.z + a0.w);
    float s1 = (a1.x + a1.y) + (a1.z + a1.w);
#pragma unroll
    for (int off = 32; off; off >>= 1) {
      s0 += __shfl_xor(s0, off, 64);
      s1 += __shfl_xor(s1, off, 64);
    }
    if (l == 0) {
      cv[c0] = fmaxf(s0 + b_enc[h0], 0.f);
      if (has1) cv[c1] = fmaxf(s1 + b_enc[h1], 0.f);
    }
  }
  __syncthreads();

  // wave 0: top-32; waves 1-3: nt-zero the z row (measured-best placement)
  if (wid == 0) {
    topk_wave0(cv, ci, cnt, sv, si, l);
  } else {
    f32x4 zz = {0.f, 0.f, 0.f, 0.f};
    f32x4* zr = (f32x4*)(zout + (size_t)b * NH);
    for (int i = tid - 64; i < NH / 4; i += 192)
      __builtin_nontemporal_store(zz, zr + i);
  }
  __syncthreads();                             // drains vmcnt -> zeros complete before scatter

  if (tid < NK) {
    int s = si[tid];
    if (s >= 0) zout[(size_t)b * NH + s] = sv[tid];
  }

  if (tid < ND / 4) {
    float4 a = ((const float4*)b_dec)[tid];
#pragma unroll 8
    for (int j = 0; j < NK; ++j) {
      int hj = si[j]; hj = (hj < 0) ? 0 : hj;
      float vj = sv[j];
      float4 wv = ((const float4*)(WdecT + (size_t)hj * ND))[tid];
      a.x = fmaf(vj, wv.x, a.x);
      a.y = fmaf(vj, wv.y, a.y);
      a.z = fmaf(vj, wv.z, a.z);
      a.w = fmaf(vj, wv.w, a.w);
    }
    ((float4*)(xhat + (size_t)b * ND))[tid] = a;
  }
}

// ---------------- K5 (fallback): finalize from cidx/ccnt ----------------
__global__ __launch_bounds__(256) void finalize_kernel(
    const float* __restrict__ x, const float* __restrict__ W_enc,
    const float* __restrict__ b_enc,
    const int* __restrict__ cand_idx, const int* __restrict__ cand_cnt,
    const float* __restrict__ WdecT, const float* __restrict__ b_dec,
    float* __restrict__ zout, float* __restrict__ xhat) {
  int b = blockIdx.x, tid = threadIdx.x;
  int wid = tid >> 6, l = tid & 63;
  __shared__ __align__(16) float xr[ND];
  __shared__ float cv[CAND_MAX];
  __shared__ int   ci[CAND_MAX];
  __shared__ float sv[NK];
  __shared__ int   si[NK];

  int cnt = cand_cnt[b];
  const float4* xrow = (const float4*)(x + (size_t)b * ND);
  for (int i = tid; i < ND / 4; i += 256) ((float4*)xr)[i] = xrow[i];
  for (int c = tid; c < cnt; c += 256) ci[c] = cand_idx[(size_t)b * CAND_MAX + c];
  __syncthreads();
  finalize_core(b, tid, wid, l, cnt, W_enc, b_enc, WdecT, b_dec,
                xr, cv, ci, sv, si, zout, xhat);
}

// ---------------- K4+K5 (fused): select+finalize ----------------
__global__ __launch_bounds__(256) void fused_finalize_kernel(
    const unsigned short* __restrict__ za,
    const float* __restrict__ x, const float* __restrict__ W_enc,
    const float* __restrict__ b_enc,
    const float* __restrict__ WdecT, const float* __restrict__ b_dec,
    float* __restrict__ zout, float* __restrict__ xhat) {
  int b = blockIdx.x, tid = threadIdx.x;
  int wid = tid >> 6, l = tid & 63;
  __shared__ __align__(16) float xr[ND];
  __shared__ float cv[CAND_MAX];
  __shared__ int   ci[CAND_MAX];
  __shared__ float sv[NK];
  __shared__ int   si[NK];
  __shared__ int   wcnt[4];
  __shared__ int   lcnt;

  const u32x4* zrow = (const u32x4*)(za + (size_t)b * NH);
  u32x4 v[8];
#pragma unroll
  for (int i = 0; i < 8; ++i) v[i] = __builtin_nontemporal_load(zrow + tid + 256 * i);
  const f32x4* xrow = (const f32x4*)(x + (size_t)b * ND);
  for (int i = tid; i < ND / 4; i += 256)
    ((f32x4*)xr)[i] = __builtin_nontemporal_load(xrow + i);

  float thr = bisect_thr(v, wcnt, tid);
  if (tid == 0) lcnt = 0;
  __syncthreads();
#pragma unroll
  for (int i = 0; i < 8; ++i) {
    const unsigned* p = (const unsigned*)&v[i];
#pragma unroll
    for (int e = 0; e < 4; ++e) {
      unsigned u = p[e];
      int hbase = (tid + 256 * i) * 8 + e * 2;
      float f0 = __uint_as_float((u & 0xFFFFu) << 16);
      float f1 = __uint_as_float(u & 0xFFFF0000u);
      if (f0 >= thr) { int s = atomicAdd(&lcnt, 1); if (s < CAND_MAX) ci[s] = hbase; }
      if (f1 >= thr) { int s = atomicAdd(&lcnt, 1); if (s < CAND_MAX) ci[s] = hbase + 1; }
    }
  }
  __syncthreads();
  int cnt = (lcnt < CAND_MAX) ? lcnt : CAND_MAX;

  finalize_core(b, tid, wid, l, cnt, W_enc, b_enc, WdecT, b_dec,
                xr, cv, ci, sv, si, zout, xhat);
}

// ---------------- launcher ----------------
extern "C" void kernel_launch(void* const* d_in, const int* in_sizes, int n_in,
                              void* d_out, int out_size, void* d_ws, size_t ws_size,
                              hipStream_t stream) {
  const float* x     = (const float*)d_in[0];
  const float* W_enc = (const float*)d_in[1];
  const float* b_enc = (const float*)d_in[2];
  const float* W_dec = (const float*)d_in[3];
  const float* b_dec = (const float*)d_in[4];

  float* xhat = (float*)d_out;
  float* zout = (float*)d_out + (size_t)NB * ND;

  char* ws = (char*)d_ws;
  unsigned short* x_bf    = (unsigned short*)(ws + OFF_XBF);
  unsigned short* wenc_bf = (unsigned short*)(ws + OFF_WENCB);
  float*          wdecT   = (float*)(ws + OFF_WDECT);
  int*            cidx    = (int*)(ws + OFF_CIDX);
  int*            ccnt    = (int*)(ws + OFF_CCNT);

  bool fused = ws_size >= OFF_ZA + ZA_BYTES;   // constant across calls -> capture-safe
  unsigned short* za = fused ? (unsigned short*)(ws + OFF_ZA)
                             : (unsigned short*)zout;

  prep_kernel<<<15360, 256, 0, stream>>>(x, x_bf, W_enc, wenc_bf, W_dec, wdecT);
  encode_gemm_kernel<<<(NB / 256) * (NH / 256), 512, 0, stream>>>(x_bf, wenc_bf, b_enc, za);
  if (fused) {
    fused_finalize_kernel<<<NB, 256, 0, stream>>>(za, x, W_enc, b_enc, wdecT, b_dec, zout, xhat);
  } else {
    select_kernel<<<NB, 256, 0, stream>>>(za, cidx, ccnt);
    finalize_kernel<<<NB, 256, 0, stream>>>(x, W_enc, b_enc, cidx, ccnt, wdecT, b_dec, zout, xhat);
  }
}

// Round 18
// 332.339 us; speedup vs baseline: 1.0240x; 1.0175x over previous
//
#include <hip/hip_runtime.h>

// K-Sparse Autoencoder fwd: B=4096, D=768, H=16384, K=32
// FINAL (round-15 measured best, 333.4us): 4-buf prefetch-3 counted-vmcnt GEMM + fused
// select/finalize with topk-slot nt-zero. Rounds 16/17 perturbations (dripped zero,
// per-phase barriers) measured null/negative and are reverted here.
// Determinism notes (tripwire discipline):
//  - no cross-call state; candidate SET deterministic; top-32 total-ordered; padding si=-1
//  - GEMM pipeline: barriers/waits wave-uniform; stage target buf (kt+3)%4 provably dead;
//    NO other VMEM ops inside the counted-vmcnt loop
//  - z zero-fill: topk slot (waves 1-3), nt stores; post-topk barrier drains before scatter
constexpr int NB = 4096;
constexpr int ND = 768;
constexpr int NH = 16384;
constexpr int NK = 32;
constexpr int CAND_MAX = 512;
#define DELTA 0.025f  // >= 2*(MFMA dot err ~0.009 + bf16 store quant ~0.004); measured-safe

typedef __bf16 bf16x8 __attribute__((ext_vector_type(8)));
typedef float  f32x4  __attribute__((ext_vector_type(4)));
typedef unsigned int u32x4 __attribute__((ext_vector_type(4)));

// ---------------- workspace layout (bytes) ----------------
constexpr size_t OFF_XBF   = 0;                                     // x bf16      [NB][ND]
constexpr size_t OFF_WENCB = OFF_XBF   + (size_t)NB * ND * 2;       // W_enc bf16  [NH][ND]
constexpr size_t OFF_WDECT = OFF_WENCB + (size_t)NH * ND * 2;       // W_dec^T f32 [NH][ND]
constexpr size_t OFF_CIDX  = OFF_WDECT + (size_t)NH * ND * 4;       // cand_idx (fallback)
constexpr size_t OFF_CCNT  = OFF_CIDX  + (size_t)NB * CAND_MAX * 4; // cand_cnt (fallback)
constexpr size_t OFF_ZA    = OFF_CCNT  + (size_t)NB * 4;            // za bf16 [NB][NH] (fused)
constexpr size_t ZA_BYTES  = (size_t)NB * NH * 2;

__device__ inline unsigned short f2bf(float f) {
  unsigned u = __float_as_uint(f);
  unsigned r = u + 0x7fffu + ((u >> 16) & 1u);   // RNE
  return (unsigned short)(r >> 16);
}

__device__ __forceinline__ void gld_lds16(const unsigned short* g, unsigned short* s) {
  __builtin_amdgcn_global_load_lds((const __attribute__((address_space(1))) void*)g,
                                   (__attribute__((address_space(3))) void*)s, 16, 0, 0);
}

// ---------------- K1: merged prep (cast x, cast W_enc, transpose W_dec) ----------------
__global__ __launch_bounds__(256) void prep_kernel(
    const float* __restrict__ x, unsigned short* __restrict__ x_bf,
    const float* __restrict__ W_enc, unsigned short* __restrict__ wenc_bf,
    const float* __restrict__ W_dec, float* __restrict__ wdecT) {
  int b = blockIdx.x, tid = threadIdx.x;
  if (b < 1024) {                       // cast x
    int n4 = NB * ND / 4, stride = 1024 * 256;
    for (int i = b * 256 + tid; i < n4; i += stride) {
      float4 v = ((const float4*)x)[i];
      unsigned long long p = (unsigned long long)f2bf(v.x)
                           | ((unsigned long long)f2bf(v.y) << 16)
                           | ((unsigned long long)f2bf(v.z) << 32)
                           | ((unsigned long long)f2bf(v.w) << 48);
      ((unsigned long long*)x_bf)[i] = p;
    }
  } else if (b < 3072) {                // cast W_enc
    int n4 = NH * ND / 4, stride = 2048 * 256;
    for (int i = (b - 1024) * 256 + tid; i < n4; i += stride) {
      float4 v = ((const float4*)W_enc)[i];
      unsigned long long p = (unsigned long long)f2bf(v.x)
                           | ((unsigned long long)f2bf(v.y) << 16)
                           | ((unsigned long long)f2bf(v.z) << 32)
                           | ((unsigned long long)f2bf(v.w) << 48);
      ((unsigned long long*)wenc_bf)[i] = p;
    }
  } else {                              // transpose W_dec: 512 x 24 tiles of 32x32
    __shared__ float tile[32][33];
    int tb = b - 3072;
    int hb = (tb & 511) * 32, db = (tb >> 9) * 32;
    int tx = tid & 31, ty = tid >> 5;   // 32 x 8
#pragma unroll
    for (int i = 0; i < 4; ++i)
      tile[ty + i * 8][tx] = W_dec[(size_t)(db + ty + i * 8) * NH + hb + tx];
    __syncthreads();
#pragma unroll
    for (int i = 0; i < 4; ++i)
      wdecT[(size_t)(hb + ty + i * 8) * ND + db + tx] = tile[tx][ty + i * 8];
  }
}

// ---------------- K3: encode GEMM 256x256, BK=32, 8 waves, 4-buffer prefetch-3 pipeline ----
__global__ __launch_bounds__(512) void encode_gemm_kernel(
    const unsigned short* __restrict__ Abf,   // [NB][ND]
    const unsigned short* __restrict__ Bbf,   // [NH][ND]
    const float* __restrict__ b_enc,
    unsigned short* __restrict__ za) {        // [NB][NH] bf16
  __shared__ __align__(16) unsigned short lds_all[4 * 16384];   // 128 KB

  int bid = blockIdx.x;                 // 0..1023
  int xx = bid & 7;
  int jj = bid >> 3;
  int st = jj >> 4;
  int w  = jj & 15;
  int g  = st * 8 + xx;
  int bm = (g & 3) * 4 + (w & 3);
  int bn = (g >> 2) * 4 + (w >> 2);
  int m0 = bm * 256, n0 = bn * 256;

  int tid = threadIdx.x;                // 0..511
  int wid = tid >> 6, l = tid & 63;
  int wr = wid >> 2, wc = wid & 3;      // 2 M-waves x 4 N-waves
  int lr = l & 15, lk = l >> 4;

#define STAGE_A(nbuf, ktile, t) do {                                              \
    int c_ = (t) * 512 + tid; int r_ = c_ >> 2;                                   \
    int lu_ = (c_ & 3) ^ ((r_ >> 1) & 3);                                         \
    gld_lds16(Abf + (size_t)(m0 + r_) * ND + (ktile) * 32 + lu_ * 8,              \
              lds_all + (nbuf) * 16384 + ((t) * 512 + (wid << 6)) * 8);           \
  } while (0)
#define STAGE_B(nbuf, ktile, t) do {                                              \
    int c_ = (t) * 512 + tid; int r_ = c_ >> 2;                                   \
    int lu_ = (c_ & 3) ^ ((r_ >> 1) & 3);                                         \
    gld_lds16(Bbf + (size_t)(n0 + r_) * ND + (ktile) * 32 + lu_ * 8,              \
              lds_all + (nbuf) * 16384 + 8192 + ((t) * 512 + (wid << 6)) * 8);    \
  } while (0)

  f32x4 acc[8][4] = {};

  STAGE_A(0, 0, 0); STAGE_A(0, 0, 1); STAGE_B(0, 0, 0); STAGE_B(0, 0, 1);
  STAGE_A(1, 1, 0); STAGE_A(1, 1, 1); STAGE_B(1, 1, 0); STAGE_B(1, 1, 1);
  STAGE_A(2, 2, 0); STAGE_A(2, 2, 1); STAGE_B(2, 2, 0); STAGE_B(2, 2, 1);
  asm volatile("s_waitcnt vmcnt(8)" ::: "memory");
  __builtin_amdgcn_s_barrier();
  __builtin_amdgcn_sched_barrier(0);

  int cur = 0;
  for (int kt = 0; kt < 24; ++kt) {     // ND/32
    int nx = (cur + 3) & 3;
    const unsigned short* Ab = lds_all + cur * 16384;
    const unsigned short* Bb = Ab + 8192;
    bf16x8 aF[4], bF[4];

#pragma unroll
    for (int fj = 0; fj < 4; ++fj) {
      int row = wc * 64 + fj * 16 + lr;
      int pu = lk ^ ((row >> 1) & 3);
      bF[fj] = *(const bf16x8*)(Bb + row * 32 + pu * 8);
    }
#pragma unroll
    for (int fi = 0; fi < 4; ++fi) {
      int row = wr * 128 + fi * 16 + lr;
      int pu = lk ^ ((row >> 1) & 3);
      aF[fi] = *(const bf16x8*)(Ab + row * 32 + pu * 8);
    }
    if (kt < 21) { STAGE_A(nx, kt + 3, 0); STAGE_A(nx, kt + 3, 1); }
    __builtin_amdgcn_s_setprio(1);
#pragma unroll
    for (int fi = 0; fi < 4; ++fi)
#pragma unroll
      for (int fj = 0; fj < 4; ++fj)
        acc[fi][fj] = __builtin_amdgcn_mfma_f32_16x16x32_bf16(aF[fi], bF[fj], acc[fi][fj], 0, 0, 0);
    __builtin_amdgcn_s_setprio(0);

#pragma unroll
    for (int fi = 0; fi < 4; ++fi) {
      int row = wr * 128 + (4 + fi) * 16 + lr;
      int pu = lk ^ ((row >> 1) & 3);
      aF[fi] = *(const bf16x8*)(Ab + row * 32 + pu * 8);
    }
    if (kt < 21) { STAGE_B(nx, kt + 3, 0); STAGE_B(nx, kt + 3, 1); }
    __builtin_amdgcn_s_setprio(1);
#pragma unroll
    for (int fi = 0; fi < 4; ++fi)
#pragma unroll
      for (int fj = 0; fj < 4; ++fj)
        acc[4 + fi][fj] = __builtin_amdgcn_mfma_f32_16x16x32_bf16(aF[fi], bF[fj], acc[4 + fi][fj], 0, 0, 0);
    __builtin_amdgcn_s_setprio(0);

    if (kt < 23) {
      if (kt <= 20)      asm volatile("s_waitcnt vmcnt(8)" ::: "memory");
      else if (kt == 21) asm volatile("s_waitcnt vmcnt(4)" ::: "memory");
      else               asm volatile("s_waitcnt vmcnt(0)" ::: "memory");
      __builtin_amdgcn_s_barrier();
      __builtin_amdgcn_sched_barrier(0);
    }
    cur = (cur + 1) & 3;
  }
#undef STAGE_A
#undef STAGE_B

  __syncthreads();
  unsigned short* ep = lds_all + wid * 4096;
#pragma unroll
  for (int half = 0; half < 2; ++half) {
#pragma unroll
    for (int fj = 0; fj < 4; ++fj) {
      float bias = b_enc[n0 + wc * 64 + fj * 16 + lr];
#pragma unroll
      for (int i2 = 0; i2 < 4; ++i2) {
#pragma unroll
        for (int q = 0; q < 4; ++q) {
          int row = i2 * 16 + lk * 4 + q;
          int col = fj * 16 + lr;
          float v = fmaxf(acc[half * 4 + i2][fj][q] + bias, 0.0f);
          ep[row * 64 + (((col >> 3) ^ (row & 7)) * 8) + (col & 7)] = f2bf(v);
        }
      }
    }
    __syncthreads();
#pragma unroll
    for (int t = 0; t < 8; ++t) {
      int row = t * 8 + (l >> 3);
      int u = (l & 7) ^ (row & 7);
      int4 d = *(const int4*)&ep[row * 64 + u * 8];
      *(int4*)(za + (size_t)(m0 + wr * 128 + half * 64 + row) * NH
                    + n0 + wc * 64 + (l & 7) * 8) = d;
    }
    __syncthreads();
  }
}

// ======== shared device helpers ========

__device__ __forceinline__ float bisect_thr(const u32x4* v, int* wcnt, int tid) {
  unsigned lo = 0u, hi = 0x7F80u;
  for (int it = 0; it < 15; ++it) {
    unsigned mid = (lo + hi) >> 1;
    int c = 0;
#pragma unroll
    for (int i = 0; i < 8; ++i) {
      const unsigned* p = (const unsigned*)&v[i];
#pragma unroll
      for (int e = 0; e < 4; ++e) {
        unsigned u = p[e];
        c += ((u & 0xFFFFu) >= mid) ? 1 : 0;
        c += ((u >> 16) >= mid) ? 1 : 0;
      }
    }
#pragma unroll
    for (int off = 32; off; off >>= 1) c += __shfl_xor(c, off, 64);
    if ((tid & 63) == 0) wcnt[tid >> 6] = c;
    __syncthreads();
    int tot = wcnt[0] + wcnt[1] + wcnt[2] + wcnt[3];
    __syncthreads();
    if (tot >= NK) {
      lo = mid;
      if (tot <= 48) break;
    } else {
      hi = mid;
    }
  }
  float thr = __uint_as_float(lo << 16) - DELTA;
  return (thr < 1e-12f) ? 1e-12f : thr;
}

__device__ __forceinline__ void topk_wave0(const float* cv, const int* ci, int cnt,
                                           float* sv, int* si, int l) {
  float lv[8]; int lh[8];
#pragma unroll
  for (int ii = 0; ii < 8; ++ii) {
    int c = l + 64 * ii;
    if (c < cnt) { lv[ii] = cv[c]; lh[ii] = ci[c]; }
    else         { lv[ii] = -1.f;  lh[ii] = 0x7fffffff; }
  }
  for (int r = 0; r < NK; ++r) {
    float bv = -1.f; int bh = 0x7fffffff; int bl = l; int bii = 0;
#pragma unroll
    for (int ii = 0; ii < 8; ++ii)
      if (lv[ii] > bv || (lv[ii] == bv && lh[ii] < bh)) { bv = lv[ii]; bh = lh[ii]; bii = ii; }
#pragma unroll
    for (int off = 32; off; off >>= 1) {
      float ov = __shfl_xor(bv, off, 64);
      int   oh = __shfl_xor(bh, off, 64);
      int   ol = __shfl_xor(bl, off, 64);
      int   oi = __shfl_xor(bii, off, 64);
      if (ov > bv || (ov == bv && oh < bh)) { bv = ov; bh = oh; bl = ol; bii = oi; }
    }
    if (l == 0) {
      if (bv > -0.5f) { sv[r] = bv; si[r] = bh; }
      else            { sv[r] = 0.f; si[r] = -1; }
    }
#pragma unroll
    for (int ii = 0; ii < 8; ++ii)
      if (ii == bii && l == bl && bv > -0.5f) lv[ii] = -1.f;
  }
}

// ---------------- K4 (fallback): select ----------------
__global__ __launch_bounds__(256) void select_kernel(const unsigned short* __restrict__ za,
                                                     int* __restrict__ cand_idx,
                                                     int* __restrict__ cand_cnt) {
  int b = blockIdx.x, tid = threadIdx.x;
  const u32x4* zrow = (const u32x4*)(za + (size_t)b * NH);
  u32x4 v[8];
#pragma unroll
  for (int i = 0; i < 8; ++i) v[i] = __builtin_nontemporal_load(zrow + tid + 256 * i);

  __shared__ int wcnt[4];
  __shared__ int lcnt;
  float thr = bisect_thr(v, wcnt, tid);
  if (tid == 0) lcnt = 0;
  __syncthreads();
#pragma unroll
  for (int i = 0; i < 8; ++i) {
    const unsigned* p = (const unsigned*)&v[i];
#pragma unroll
    for (int e = 0; e < 4; ++e) {
      unsigned u = p[e];
      int hbase = (tid + 256 * i) * 8 + e * 2;
      float f0 = __uint_as_float((u & 0xFFFFu) << 16);
      float f1 = __uint_as_float(u & 0xFFFF0000u);
      if (f0 >= thr) { int s = atomicAdd(&lcnt, 1); if (s < CAND_MAX) cand_idx[(size_t)b * CAND_MAX + s] = hbase; }
      if (f1 >= thr) { int s = atomicAdd(&lcnt, 1); if (s < CAND_MAX) cand_idx[(size_t)b * CAND_MAX + s] = hbase + 1; }
    }
  }
  __syncthreads();
  if (tid == 0) cand_cnt[b] = (lcnt < CAND_MAX) ? lcnt : CAND_MAX;
}

// ======== finalize core: ILP-2 gather -> {topk || nt-zero} -> scatter + decode ========
__device__ __forceinline__ void finalize_core(
    int b, int tid, int wid, int l, int cnt,
    const float* __restrict__ W_enc, const float* __restrict__ b_enc,
    const float* __restrict__ WdecT, const float* __restrict__ b_dec,
    const float* xr, float* cv, const int* ci, float* sv, int* si,
    float* __restrict__ zout, float* __restrict__ xhat) {
  const float4* xr4 = (const float4*)xr;
  float4 xv[3];
#pragma unroll
  for (int i = 0; i < 3; ++i) xv[i] = xr4[l + 64 * i];

  for (int c0 = wid; c0 < cnt; c0 += 8) {     // 2 candidates per iteration (ILP)
    int c1 = c0 + 4;
    bool has1 = (c1 < cnt);
    int h0 = ci[c0];
    int h1 = has1 ? ci[c1] : h0;
    const float4* w0 = (const float4*)(W_enc + (size_t)h0 * ND);
    const float4* w1 = (const float4*)(W_enc + (size_t)h1 * ND);
    float4 wv0[3], wv1[3];
#pragma unroll
    for (int i = 0; i < 3; ++i) { wv0[i] = w0[l + 64 * i]; wv1[i] = w1[l + 64 * i]; }
    float4 a0 = {0.f, 0.f, 0.f, 0.f}, a1 = {0.f, 0.f, 0.f, 0.f};
#pragma unroll
    for (int i = 0; i < 3; ++i) {
      a0.x = fmaf(wv0[i].x, xv[i].x, a0.x); a1.x = fmaf(wv1[i].x, xv[i].x, a1.x);
      a0.y = fmaf(wv0[i].y, xv[i].y, a0.y); a1.y = fmaf(wv1[i].y, xv[i].y, a1.y);
      a0.z = fmaf(wv0[i].z, xv[i].z, a0.z); a1.z = fmaf(wv1[i].z, xv[i].z, a1.z);
      a0.w = fmaf(wv0[i].w, xv[i].w, a0.w); a1.w = fmaf(wv1[i].w, xv[i].w, a1.w);
    }
    float s0 = (a0.x + a0.y) + (a0.z + a0.w);
    float s1 = (a1.x + a1.y) + (a1.z + a1.w);
#pragma unroll
    for (int off = 32; off; off >>= 1) {
      s0 += __shfl_xor(s0, off, 64);
      s1 += __shfl_xor(s1, off, 64);
    }
    if (l == 0) {
      cv[c0] = fmaxf(s0 + b_enc[h0], 0.f);
      if (has1) cv[c1] = fmaxf(s1 + b_enc[h1], 0.f);
    }
  }
  __syncthreads();

  // wave 0: top-32; waves 1-3: nt-zero the z row (measured-best placement)
  if (wid == 0) {
    topk_wave0(cv, ci, cnt, sv, si, l);
  } else {
    f32x4 zz = {0.f, 0.f, 0.f, 0.f};
    f32x4* zr = (f32x4*)(zout + (size_t)b * NH);
    for (int i = tid - 64; i < NH / 4; i += 192)
      __builtin_nontemporal_store(zz, zr + i);
  }
  __syncthreads();                             // drains vmcnt -> zeros complete before scatter

  if (tid < NK) {
    int s = si[tid];
    if (s >= 0) zout[(size_t)b * NH + s] = sv[tid];
  }

  if (tid < ND / 4) {
    float4 a = ((const float4*)b_dec)[tid];
#pragma unroll 8
    for (int j = 0; j < NK; ++j) {
      int hj = si[j]; hj = (hj < 0) ? 0 : hj;
      float vj = sv[j];
      float4 wv = ((const float4*)(WdecT + (size_t)hj * ND))[tid];
      a.x = fmaf(vj, wv.x, a.x);
      a.y = fmaf(vj, wv.y, a.y);
      a.z = fmaf(vj, wv.z, a.z);
      a.w = fmaf(vj, wv.w, a.w);
    }
    ((float4*)(xhat + (size_t)b * ND))[tid] = a;
  }
}

// ---------------- K5 (fallback): finalize from cidx/ccnt ----------------
__global__ __launch_bounds__(256) void finalize_kernel(
    const float* __restrict__ x, const float* __restrict__ W_enc,
    const float* __restrict__ b_enc,
    const int* __restrict__ cand_idx, const int* __restrict__ cand_cnt,
    const float* __restrict__ WdecT, const float* __restrict__ b_dec,
    float* __restrict__ zout, float* __restrict__ xhat) {
  int b = blockIdx.x, tid = threadIdx.x;
  int wid = tid >> 6, l = tid & 63;
  __shared__ __align__(16) float xr[ND];
  __shared__ float cv[CAND_MAX];
  __shared__ int   ci[CAND_MAX];
  __shared__ float sv[NK];
  __shared__ int   si[NK];

  int cnt = cand_cnt[b];
  const float4* xrow = (const float4*)(x + (size_t)b * ND);
  for (int i = tid; i < ND / 4; i += 256) ((float4*)xr)[i] = xrow[i];
  for (int c = tid; c < cnt; c += 256) ci[c] = cand_idx[(size_t)b * CAND_MAX + c];
  __syncthreads();
  finalize_core(b, tid, wid, l, cnt, W_enc, b_enc, WdecT, b_dec,
                xr, cv, ci, sv, si, zout, xhat);
}

// ---------------- K4+K5 (fused): select+finalize ----------------
__global__ __launch_bounds__(256) void fused_finalize_kernel(
    const unsigned short* __restrict__ za,
    const float* __restrict__ x, const float* __restrict__ W_enc,
    const float* __restrict__ b_enc,
    const float* __restrict__ WdecT, const float* __restrict__ b_dec,
    float* __restrict__ zout, float* __restrict__ xhat) {
  int b = blockIdx.x, tid = threadIdx.x;
  int wid = tid >> 6, l = tid & 63;
  __shared__ __align__(16) float xr[ND];
  __shared__ float cv[CAND_MAX];
  __shared__ int   ci[CAND_MAX];
  __shared__ float sv[NK];
  __shared__ int   si[NK];
  __shared__ int   wcnt[4];
  __shared__ int   lcnt;

  const u32x4* zrow = (const u32x4*)(za + (size_t)b * NH);
  u32x4 v[8];
#pragma unroll
  for (int i = 0; i < 8; ++i) v[i] = __builtin_nontemporal_load(zrow + tid + 256 * i);
  const f32x4* xrow = (const f32x4*)(x + (size_t)b * ND);
  for (int i = tid; i < ND / 4; i += 256)
    ((f32x4*)xr)[i] = __builtin_nontemporal_load(xrow + i);

  float thr = bisect_thr(v, wcnt, tid);
  if (tid == 0) lcnt = 0;
  __syncthreads();
#pragma unroll
  for (int i = 0; i < 8; ++i) {
    const unsigned* p = (const unsigned*)&v[i];
#pragma unroll
    for (int e = 0; e < 4; ++e) {
      unsigned u = p[e];
      int hbase = (tid + 256 * i) * 8 + e * 2;
      float f0 = __uint_as_float((u & 0xFFFFu) << 16);
      float f1 = __uint_as_float(u & 0xFFFF0000u);
      if (f0 >= thr) { int s = atomicAdd(&lcnt, 1); if (s < CAND_MAX) ci[s] = hbase; }
      if (f1 >= thr) { int s = atomicAdd(&lcnt, 1); if (s < CAND_MAX) ci[s] = hbase + 1; }
    }
  }
  __syncthreads();
  int cnt = (lcnt < CAND_MAX) ? lcnt : CAND_MAX;

  finalize_core(b, tid, wid, l, cnt, W_enc, b_enc, WdecT, b_dec,
                xr, cv, ci, sv, si, zout, xhat);
}

// ---------------- launcher ----------------
extern "C" void kernel_launch(void* const* d_in, const int* in_sizes, int n_in,
                              void* d_out, int out_size, void* d_ws, size_t ws_size,
                              hipStream_t stream) {
  const float* x     = (const float*)d_in[0];
  const float* W_enc = (const float*)d_in[1];
  const float* b_enc = (const float*)d_in[2];
  const float* W_dec = (const float*)d_in[3];
  const float* b_dec = (const float*)d_in[4];

  float* xhat = (float*)d_out;
  float* zout = (float*)d_out + (size_t)NB * ND;

  char* ws = (char*)d_ws;
  unsigned short* x_bf    = (unsigned short*)(ws + OFF_XBF);
  unsigned short* wenc_bf = (unsigned short*)(ws + OFF_WENCB);
  float*          wdecT   = (float*)(ws + OFF_WDECT);
  int*            cidx    = (int*)(ws + OFF_CIDX);
  int*            ccnt    = (int*)(ws + OFF_CCNT);

  bool fused = ws_size >= OFF_ZA + ZA_BYTES;   // constant across calls -> capture-safe
  unsigned short* za = fused ? (unsigned short*)(ws + OFF_ZA)
                             : (unsigned short*)zout;

  prep_kernel<<<15360, 256, 0, stream>>>(x, x_bf, W_enc, wenc_bf, W_dec, wdecT);
  encode_gemm_kernel<<<(NB / 256) * (NH / 256), 512, 0, stream>>>(x_bf, wenc_bf, b_enc, za);
  if (fused) {
    fused_finalize_kernel<<<NB, 256, 0, stream>>>(za, x, W_enc, b_enc, wdecT, b_dec, zout, xhat);
  } else {
    select_kernel<<<NB, 256, 0, stream>>>(za, cidx, ccnt);
    finalize_kernel<<<NB, 256, 0, stream>>>(x, W_enc, b_enc, cidx, ccnt, wdecT, b_dec, zout, xhat);
  }
}